// Round 6
// baseline (127.774 us; speedup 1.0000x reference)
//
#include <hip/hip_runtime.h>

#define NODES 50000
#define NA    65
#define NDEG  32

// Inputs f32 (R2 probe). Output f32.
// R5 -> R6: block-cooperative gather staging. Block = 32 nodes x 8 threads.
//  - Stage B: 256 threads gather all 32x32 rel pairs once into LDS
//    (4 loads/thread vs 64 in R5 -- the 8-way gather duplication is gone).
//  - relbuf stride = 34 float2/node (272 B): 8 concurrent node-groups hit
//    distinct banks; same-node 8-lane reads are same-address broadcast.
//  - Layer 2 packed over j: acc_c = sum_p h1v[p] * w2_p_c, horizontal add
//    at the end -- removes the 16 splat v_movs/neighbor of R5.
//  - W2 slice kept in NAMED v2f regs (R3: arrays spilled -> 95 MB WRITE).

typedef float v2f __attribute__((ext_vector_type(2)));

static __device__ __forceinline__ v2f pk_fma(v2f a, v2f b, v2f c) {
    return __builtin_elementwise_fma(a, b, c);
}
static __device__ __forceinline__ v2f pk_max(v2f a, v2f b) {
    return __builtin_elementwise_max(a, b);
}

#define RELSTRIDE 34   // 32 + 2 pad: 272 B/node -> bank shift 4/node, 16B aligned

__global__ __launch_bounds__(256, 1) void fused_kernel(
    const float* __restrict__ corr,   // (N, 65, 2)
    const int*   __restrict__ nei,    // (N, 32, 3)
    const float* __restrict__ W_se,   // (2, 32)
    const float* __restrict__ b_se,   // (32)
    const float* __restrict__ W1,     // (32, 16)
    const float* __restrict__ b1,     // (16)
    const float* __restrict__ W2,     // (16, 32)
    const float* __restrict__ b2,     // (32)
    float* __restrict__ out)          // (N, 32)
{
    __shared__ __align__(16) float  fold[48];
    __shared__ __align__(16) float2 relbuf[32 * RELSTRIDE];

    int t  = threadIdx.x;
    int nb = blockIdx.x * 32;

    // ---- fold W_se@W1 (32) and b_se@W1+b1 (16) ----
    if (t < 48) {
        float s;
        if (t < 32) {
            int c = t >> 4, j = t & 15;
            s = 0.0f;
#pragma unroll
            for (int e = 0; e < 32; ++e)
                s = fmaf(W_se[c * 32 + e], W1[e * 16 + j], s);
        } else {
            int j = t - 32;
            s = b1[j];
#pragma unroll
            for (int e = 0; e < 32; ++e)
                s = fmaf(b_se[e], W1[e * 16 + j], s);
        }
        fold[t] = s;
    }

    // ---- cooperative gather: 1024 slots, 4 per thread, g = t + 256u ----
    // lanes of one instruction cover 2 consecutive nodes -> idx loads span
    // ~768B (coalesced); gathers cluster within two 520B corr rows (L1).
#pragma unroll
    for (int u = 0; u < 4; ++u) {
        int g    = t + 256 * u;
        int nl   = g >> 5;
        int d    = g & 31;
        int node = nb + nl;
        if (node < NODES) {
            int idx = nei[((size_t)node * NDEG + d) * 3 + 1];
            relbuf[nl * RELSTRIDE + d] =
                ((const float2*)corr)[(size_t)node * NA + idx];
        }
    }
    __syncthreads();

    int nl   = t >> 3;
    int node = nb + nl;
    int k0   = (t & 7) * 4;
    if (node >= NODES) return;   // after barrier: safe

    // ---- layer-1 weights -> registers (24 v2f) ----
    v2f wc0v[8], wc1v[8], bcv[8];
    {
        const v2f* fv = (const v2f*)fold;
#pragma unroll
        for (int j = 0; j < 8; ++j) {
            wc0v[j] = fv[j];
            wc1v[j] = fv[8 + j];
            bcv[j]  = fv[16 + j];
        }
    }

    // ---- W2 slice transposed-over-j: 32 NAMED v2f ----
    // w2_p_c = { W2[2p][k0+c], W2[2p+1][k0+c] }
#define W2T(p)                                                              \
    float4 ra_##p = *(const float4*)(W2 + (2 * (p)) * 32 + k0);             \
    float4 rb_##p = *(const float4*)(W2 + (2 * (p) + 1) * 32 + k0);         \
    v2f w2_##p##_0 = {ra_##p.x, rb_##p.x};                                  \
    v2f w2_##p##_1 = {ra_##p.y, rb_##p.y};                                  \
    v2f w2_##p##_2 = {ra_##p.z, rb_##p.z};                                  \
    v2f w2_##p##_3 = {ra_##p.w, rb_##p.w};
    W2T(0) W2T(1) W2T(2) W2T(3) W2T(4) W2T(5) W2T(6) W2T(7)
#undef W2T

    float4 b2v = *(const float4*)(b2 + k0);

    float vm0 = 0.0f, vm1 = 0.0f, vm2 = 0.0f, vm3 = 0.0f;  // relu/max fold

    const float2* rp = relbuf + nl * RELSTRIDE;

#define L2P(p) do {                                                         \
        acc0 = pk_fma(h1v[p], w2_##p##_0, acc0);                            \
        acc1 = pk_fma(h1v[p], w2_##p##_1, acc1);                            \
        acc2 = pk_fma(h1v[p], w2_##p##_2, acc2);                            \
        acc3 = pk_fma(h1v[p], w2_##p##_3, acc3);                            \
    } while (0)

#pragma unroll
    for (int d = 0; d < NDEG; ++d) {
        float2 r = rp[d];                     // 8-lane broadcast, banks padded
        v2f r0s = {r.x, r.x}, r1s = {r.y, r.y};
        v2f h1v[8];
#pragma unroll
        for (int j = 0; j < 8; ++j)
            h1v[j] = pk_max((v2f)(0.0f),
                     pk_fma(r0s, wc0v[j], pk_fma(r1s, wc1v[j], bcv[j])));
        v2f acc0 = {b2v.x, 0.0f}, acc1 = {b2v.y, 0.0f};
        v2f acc2 = {b2v.z, 0.0f}, acc3 = {b2v.w, 0.0f};
        L2P(0); L2P(1); L2P(2); L2P(3); L2P(4); L2P(5); L2P(6); L2P(7);
        vm0 = fmaxf(vm0, acc0.x + acc0.y);
        vm1 = fmaxf(vm1, acc1.x + acc1.y);
        vm2 = fmaxf(vm2, acc2.x + acc2.y);
        vm3 = fmaxf(vm3, acc3.x + acc3.y);
    }
#undef L2P

    // ---- coalesced store: wave writes 64 x 16B contiguous ----
    *(float4*)(out + (size_t)node * 32 + k0) = make_float4(vm0, vm1, vm2, vm3);
}

extern "C" void kernel_launch(void* const* d_in, const int* in_sizes, int n_in,
                              void* d_out, int out_size, void* d_ws, size_t ws_size,
                              hipStream_t stream) {
    const float* corr = (const float*)d_in[0];
    const int*   nei  = (const int*)d_in[1];
    // d_in[2] = lstm_state: dead input (unused by the reference output)
    const float* W_se = (const float*)d_in[3];
    const float* b_se = (const float*)d_in[4];
    const float* W1   = (const float*)d_in[5];
    const float* b1   = (const float*)d_in[6];
    const float* W2   = (const float*)d_in[7];
    const float* b2   = (const float*)d_in[8];
    float* out = (float*)d_out;

    int blocks = (NODES + 31) / 32;   // 32 nodes per block
    hipLaunchKernelGGL(fused_kernel, dim3(blocks), dim3(256), 0, stream,
                       corr, nei, W_se, b_se, W1, b1, W2, b2, out);
}

// Round 7
// 105.002 us; speedup vs baseline: 1.2169x; 1.2169x over previous
//
#include <hip/hip_runtime.h>
#include <hip/hip_bf16.h>

#define NODES 50000
#define NA    65
#define NDEG  32

// Inputs f32 (R2 probe). Output f32.
// R6 -> R7: layer 2 moved to the matrix pipe.
//   Per node: h1(32 nei x 16 hid) @ W2(16 x 32 ch) = ONE v_mfma_f32_32x32x16_bf16
//   (M=neighbors, N=channels, K=hidden). Replaces 256 packed-VALU instr/node.
//   Layer 1 stays f32 VALU (K=2, not MFMA-shaped); h1 -> bf16 RNE after relu.
//   Max over rows is permutation-invariant -> C/D row mapping can't hurt us.
//   b2 added AFTER the max (commutes); relu folded via fmax(0, .).
// Block = 32 nodes x 256 thr (4 waves x 8 nodes); R6's cooperative staging kept.

typedef float v2f __attribute__((ext_vector_type(2)));
typedef __attribute__((ext_vector_type(8))) short short8;     // 8 bf16 = 4 VGPRs
typedef __attribute__((ext_vector_type(16))) float f32x16;    // MFMA C/D

static __device__ __forceinline__ v2f pk_fma(v2f a, v2f b, v2f c) {
    return __builtin_elementwise_fma(a, b, c);
}
static __device__ __forceinline__ v2f pk_max(v2f a, v2f b) {
    return __builtin_elementwise_max(a, b);
}

__global__ __launch_bounds__(256, 1) void fused_kernel(
    const float* __restrict__ corr,   // (N, 65, 2)
    const int*   __restrict__ nei,    // (N, 32, 3)
    const float* __restrict__ W_se,   // (2, 32)
    const float* __restrict__ b_se,   // (32)
    const float* __restrict__ W1,     // (32, 16)
    const float* __restrict__ b1,     // (16)
    const float* __restrict__ W2,     // (16, 32)
    const float* __restrict__ b2,     // (32)
    float* __restrict__ out)          // (N, 32)
{
    __shared__ __align__(16) float  fold[48];
    __shared__ __align__(16) float2 relbuf[32 * 32];   // stride 32: 2-way LDS alias = free

    int t  = threadIdx.x;
    int nb = blockIdx.x * 32;

    // ---- fold W_se@W1 (32) and b_se@W1+b1 (16) ----
    if (t < 48) {
        float s;
        if (t < 32) {                       // fold[c*16+j] = Wc[c][j]
            int c = t >> 4, j = t & 15;
            s = 0.0f;
#pragma unroll
            for (int e = 0; e < 32; ++e)
                s = fmaf(W_se[c * 32 + e], W1[e * 16 + j], s);
        } else {                            // fold[32+j] = bc[j]
            int j = t - 32;
            s = b1[j];
#pragma unroll
            for (int e = 0; e < 32; ++e)
                s = fmaf(b_se[e], W1[e * 16 + j], s);
        }
        fold[t] = s;
    }

    // ---- cooperative gather: 1024 rel pairs, 4 per thread (R6 pattern) ----
#pragma unroll
    for (int u = 0; u < 4; ++u) {
        int g    = t + 256 * u;
        int nl   = g >> 5;
        int d    = g & 31;
        int node = nb + nl;
        if (node < NODES) {
            int idx = nei[((size_t)node * NDEG + d) * 3 + 1];
            relbuf[nl * 32 + d] = ((const float2*)corr)[(size_t)node * NA + idx];
        }
    }
    __syncthreads();

    int lane  = t & 63;
    int w     = t >> 6;        // wave id 0..3 -> nodes w*8..w*8+7
    int col   = lane & 31;     // = m for A (neighbor), = n for B/C (channel)
    int khalf = lane >> 5;     // k-chunk: lanes 0-31 -> k 0..7, lanes 32-63 -> k 8..15

    // ---- per-lane layer-1 weights for its 8 k's, as v2f pairs ----
    v2f wc0v[4], wc1v[4], bcv[4];
    {
        const float* fb = fold + khalf * 8;
#pragma unroll
        for (int p = 0; p < 4; ++p) {
            wc0v[p] = *(const v2f*)(fb + 2 * p);
            wc1v[p] = *(const v2f*)(fb + 16 + 2 * p);
            bcv[p]  = *(const v2f*)(fb + 32 + 2 * p);
        }
    }

    // ---- B fragment: B[k=khalf*8+j][n=col] = W2[k][col], bf16 RNE ----
    union FragU { short8 s8; __hip_bfloat162 h2[4]; };
    FragU bu;
#pragma unroll
    for (int p = 0; p < 4; ++p) {
        int k = khalf * 8 + 2 * p;
        bu.h2[p] = __float22bfloat162_rn(
            make_float2(W2[k * 32 + col], W2[(k + 1) * 32 + col]));
    }
    float b2c = b2[col];

    f32x16 czero;
#pragma unroll
    for (int j = 0; j < 16; ++j) czero[j] = 0.0f;

    const float2* rp = relbuf + w * 8 * 32;

#pragma unroll
    for (int i = 0; i < 8; ++i) {
        int node = nb + w * 8 + i;
        if (node >= NODES) break;   // wave-uniform branch

        // this lane's neighbor rel (8-lane... here 2-lane same-addr broadcast)
        float2 r = rp[i * 32 + col];
        v2f r0s = {r.x, r.x}, r1s = {r.y, r.y};

        // layer 1 (f32): h1[k] = relu(r0*Wc0[k] + r1*Wc1[k] + bc[k]), 8 k's
        FragU au;
#pragma unroll
        for (int p = 0; p < 4; ++p) {
            v2f h = pk_max((v2f)(0.0f),
                     pk_fma(r0s, wc0v[p], pk_fma(r1s, wc1v[p], bcv[p])));
            au.h2[p] = __float22bfloat162_rn(make_float2(h.x, h.y));
        }

        // layer 2: D = A(32x16) * B(16x32), f32 accumulate
        f32x16 acc = __builtin_amdgcn_mfma_f32_32x32x16_bf16(au.s8, bu.s8, czero, 0, 0, 0);

        // max over the 16 rows this lane holds (row order irrelevant for max)
        float m = acc[0];
#pragma unroll
        for (int j = 1; j < 16; ++j) m = fmaxf(m, acc[j]);
        // other 16 rows live in partner lane (same col, lane^32)
        m = fmaxf(m, __shfl_xor(m, 32, 64));

        float res = fmaxf(0.0f, m + b2c);    // b2 after max; relu/neginf fold
        if (lane < 32) out[(size_t)node * 32 + col] = res;  // 128B per node
    }
}

extern "C" void kernel_launch(void* const* d_in, const int* in_sizes, int n_in,
                              void* d_out, int out_size, void* d_ws, size_t ws_size,
                              hipStream_t stream) {
    const float* corr = (const float*)d_in[0];
    const int*   nei  = (const int*)d_in[1];
    // d_in[2] = lstm_state: dead input (unused by the reference output)
    const float* W_se = (const float*)d_in[3];
    const float* b_se = (const float*)d_in[4];
    const float* W1   = (const float*)d_in[5];
    const float* b1   = (const float*)d_in[6];
    const float* W2   = (const float*)d_in[7];
    const float* b2   = (const float*)d_in[8];
    float* out = (float*)d_out;

    int blocks = (NODES + 31) / 32;   // 32 nodes per block
    hipLaunchKernelGGL(fused_kernel, dim3(blocks), dim3(256), 0, stream,
                       corr, nei, W_se, b_se, W1, b1, W2, b2, out);
}

// Round 8
// 104.963 us; speedup vs baseline: 1.2173x; 1.0004x over previous
//
#include <hip/hip_runtime.h>
#include <hip/hip_bf16.h>

#define NODES 50000
#define NA    65
#define NDEG  32

// Inputs f32 (R2 probe). Output f32.
// R7 -> R8: remove the LDS rel-staging phase entirely.
//   In the MFMA decomposition each lane consumes exactly ONE rel pair per
//   node (col = lane&31) -- there is no cross-lane reuse, so LDS staging
//   only added a barrier + serialized idx->gather latency (R7 ~25us).
//   Now: 8 independent idx loads issue BEFORE the fold barrier, 8 gathers
//   right after -- 16 loads in flight, latency pipelined, LDS = 192B.
//   Layer 2 stays one v_mfma_f32_32x32x16_bf16 per node (M=nei, N=ch, K=hid).
//   Max-reduce: pk_max tree (7 v_pk_max_f32 + 1 fmax) instead of 15 serial.
//   b2 added after max (commutes); relu/neginf fold as before.

typedef float v2f __attribute__((ext_vector_type(2)));
typedef __attribute__((ext_vector_type(8))) short short8;     // 8 bf16 = 4 VGPRs
typedef __attribute__((ext_vector_type(16))) float f32x16;    // MFMA C/D

static __device__ __forceinline__ v2f pk_fma(v2f a, v2f b, v2f c) {
    return __builtin_elementwise_fma(a, b, c);
}
static __device__ __forceinline__ v2f pk_max(v2f a, v2f b) {
    return __builtin_elementwise_max(a, b);
}

__global__ __launch_bounds__(256, 1) void fused_kernel(
    const float* __restrict__ corr,   // (N, 65, 2)
    const int*   __restrict__ nei,    // (N, 32, 3)
    const float* __restrict__ W_se,   // (2, 32)
    const float* __restrict__ b_se,   // (32)
    const float* __restrict__ W1,     // (32, 16)
    const float* __restrict__ b1,     // (16)
    const float* __restrict__ W2,     // (16, 32)
    const float* __restrict__ b2,     // (32)
    float* __restrict__ out)          // (N, 32)
{
    __shared__ __align__(16) float fold[48];

    int t     = threadIdx.x;
    int lane  = t & 63;
    int w     = t >> 6;              // wave id: nodes w*8 .. w*8+7 of this block
    int col   = lane & 31;           // m (neighbor) for A, n (channel) for B/C
    int khalf = lane >> 5;           // k-chunk: 0 -> k 0..7, 1 -> k 8..15
    int nbase = blockIdx.x * 32 + w * 8;

    // ---- issue all 8 idx loads FIRST (independent, coalesced 384B span) ----
    int idxv[8];
#pragma unroll
    for (int i = 0; i < 8; ++i) {
        int node = nbase + i; if (node > NODES - 1) node = NODES - 1;
        idxv[i] = nei[((size_t)node * NDEG + col) * 3 + 1];
    }

    // ---- fold W_se@W1 (32) and b_se@W1+b1 (16); overlaps idx latency ----
    if (t < 48) {
        float s;
        if (t < 32) {                       // fold[c*16+j] = Wc[c][j]
            int c = t >> 4, j = t & 15;
            s = 0.0f;
#pragma unroll
            for (int e = 0; e < 32; ++e)
                s = fmaf(W_se[c * 32 + e], W1[e * 16 + j], s);
        } else {                            // fold[32+j] = bc[j]
            int j = t - 32;
            s = b1[j];
#pragma unroll
            for (int e = 0; e < 32; ++e)
                s = fmaf(b_se[e], W1[e * 16 + j], s);
        }
        fold[t] = s;
    }

    // ---- 8 independent rel gathers (each within one 520B corr row) ----
    float2 rel[8];
#pragma unroll
    for (int i = 0; i < 8; ++i) {
        int node = nbase + i; if (node > NODES - 1) node = NODES - 1;
        rel[i] = ((const float2*)corr)[(size_t)node * NA + idxv[i]];
    }

    // ---- B fragment: B[k=khalf*8+j][n=col] = W2[k][col], bf16 RNE ----
    union FragU { short8 s8; __hip_bfloat162 h2[4]; };
    FragU bu;
#pragma unroll
    for (int p = 0; p < 4; ++p) {
        int k = khalf * 8 + 2 * p;
        bu.h2[p] = __float22bfloat162_rn(
            make_float2(W2[k * 32 + col], W2[(k + 1) * 32 + col]));
    }
    float b2c = b2[col];

    __syncthreads();

    // ---- per-lane layer-1 weights for its 8 k's ----
    v2f wc0v[4], wc1v[4], bcv[4];
    {
        const float* fb = fold + khalf * 8;
#pragma unroll
        for (int p = 0; p < 4; ++p) {
            wc0v[p] = *(const v2f*)(fb + 2 * p);
            wc1v[p] = *(const v2f*)(fb + 16 + 2 * p);
            bcv[p]  = *(const v2f*)(fb + 32 + 2 * p);
        }
    }

    f32x16 czero;
#pragma unroll
    for (int j = 0; j < 16; ++j) czero[j] = 0.0f;

#pragma unroll
    for (int i = 0; i < 8; ++i) {
        int node = nbase + i;

        v2f r0s = {rel[i].x, rel[i].x}, r1s = {rel[i].y, rel[i].y};

        // layer 1 (f32): h1[k] = relu(r0*Wc0[k] + r1*Wc1[k] + bc[k]), 8 k's
        FragU au;
#pragma unroll
        for (int p = 0; p < 4; ++p) {
            v2f h = pk_max((v2f)(0.0f),
                     pk_fma(r0s, wc0v[p], pk_fma(r1s, wc1v[p], bcv[p])));
            au.h2[p] = __float22bfloat162_rn(make_float2(h.x, h.y));
        }

        // layer 2: D(32x32) = A(32x16) @ B(16x32), f32 accumulate
        f32x16 acc = __builtin_amdgcn_mfma_f32_32x32x16_bf16(au.s8, bu.s8, czero, 0, 0, 0);

        // max over this lane's 16 rows: packed tree (rows permute-invariant)
        v2f p0 = pk_max((v2f){acc[0],  acc[1]},  (v2f){acc[2],  acc[3]});
        v2f p1 = pk_max((v2f){acc[4],  acc[5]},  (v2f){acc[6],  acc[7]});
        v2f p2 = pk_max((v2f){acc[8],  acc[9]},  (v2f){acc[10], acc[11]});
        v2f p3 = pk_max((v2f){acc[12], acc[13]}, (v2f){acc[14], acc[15]});
        v2f q0 = pk_max(p0, p1);
        v2f q1 = pk_max(p2, p3);
        v2f rr = pk_max(q0, q1);
        float m = fmaxf(rr.x, rr.y);
        // other 16 rows live in the partner lane (same col, lane^32)
        m = fmaxf(m, __shfl_xor(m, 32, 64));

        float res = fmaxf(0.0f, m + b2c);    // b2 after max; relu/neginf fold
        if (lane < 32 && node < NODES)
            out[(size_t)node * 32 + col] = res;   // 128B per node, coalesced
    }
}

extern "C" void kernel_launch(void* const* d_in, const int* in_sizes, int n_in,
                              void* d_out, int out_size, void* d_ws, size_t ws_size,
                              hipStream_t stream) {
    const float* corr = (const float*)d_in[0];
    const int*   nei  = (const int*)d_in[1];
    // d_in[2] = lstm_state: dead input (unused by the reference output)
    const float* W_se = (const float*)d_in[3];
    const float* b_se = (const float*)d_in[4];
    const float* W1   = (const float*)d_in[5];
    const float* b1   = (const float*)d_in[6];
    const float* W2   = (const float*)d_in[7];
    const float* b2   = (const float*)d_in[8];
    float* out = (float*)d_out;

    int blocks = (NODES + 31) / 32;   // 32 nodes per block (4 waves x 8 nodes)
    hipLaunchKernelGGL(fused_kernel, dim3(blocks), dim3(256), 0, stream,
                       corr, nei, W_se, b_se, W1, b1, W2, b2, out);
}